// Round 10
// baseline (254.255 us; speedup 1.0000x reference)
//
#include <hip/hip_runtime.h>
#include <math.h>

#define SEQ   2048
#define DM    1024
#define MTOT  4096      // batch * seq
#define NHEAD 16
#define DHEAD 64
#define ROPE_C 0.41524101186091903f   // log2(10000)/32
#define XN    (MTOT * DM)             // 4194304
#define WN    (DM * DM)               // 1048576
#define CVT_BLOCKS ((XN + 4 * WN) / (8 * 256))   // 4096
#define TAB_N      (SEQ * 32)                    // 65536 float2

typedef __bf16 bf16x8 __attribute__((ext_vector_type(8)));
typedef float  f32x4  __attribute__((ext_vector_type(4)));

// async global->LDS, 16 B/lane; lds dest = wave-uniform base + lane*16
__device__ __forceinline__ void gll16(const __bf16* gp, __bf16* lp) {
    __builtin_amdgcn_global_load_lds(
        (const __attribute__((address_space(1))) unsigned int*)gp,
        (__attribute__((address_space(3))) unsigned int*)lp,
        16, 0, 0);
}

// -------- fp32 -> bf16 conversion of x + 4 weights, and RoPE sin/cos table ------------
__global__ __launch_bounds__(256) void cvt_kernel(
    const float* __restrict__ x,  const float* __restrict__ wq,
    const float* __restrict__ wk, const float* __restrict__ wv,
    const float* __restrict__ wo, const int* __restrict__ pos,
    __bf16* __restrict__ xb,  __bf16* __restrict__ wqb,
    __bf16* __restrict__ wkb, __bf16* __restrict__ wvb,
    __bf16* __restrict__ wob, float2* __restrict__ sc)
{
    if (blockIdx.x >= CVT_BLOCKS) {   // sin/cos table: sc[s][ip] = (cos, sin)
        const int idx = (blockIdx.x - CVT_BLOCKS) * 256 + threadIdx.x;
        if (idx < TAB_N) {
            const int p_i = idx >> 5, ip = idx & 31;
            const float ang = (float)pos[p_i] * exp2f(-(float)ip * ROPE_C);
            float sn, cs;
            sincosf(ang, &sn, &cs);
            sc[idx] = make_float2(cs, sn);
        }
        return;
    }
    const size_t i8 = ((size_t)blockIdx.x * 256 + threadIdx.x) * 8;
    const float* s; __bf16* d; size_t off;
    if      (i8 < XN)          { s = x;  d = xb;  off = i8; }
    else if (i8 < XN + WN)     { s = wq; d = wqb; off = i8 - XN; }
    else if (i8 < XN + 2 * WN) { s = wk; d = wkb; off = i8 - XN - (size_t)WN; }
    else if (i8 < XN + 3 * WN) { s = wv; d = wvb; off = i8 - XN - 2 * (size_t)WN; }
    else                       { s = wo; d = wob; off = i8 - XN - 3 * (size_t)WN; }
    const float4 a = *(const float4*)(s + off);
    const float4 b = *(const float4*)(s + off + 4);
    __bf16 o[8] = {(__bf16)a.x, (__bf16)a.y, (__bf16)a.z, (__bf16)a.w,
                   (__bf16)b.x, (__bf16)b.y, (__bf16)b.z, (__bf16)b.w};
    *(float4*)(d + off) = *(float4*)o;
}

// ---------------- MFMA GEMM: C[M,1024] = A[M,1024] @ B[1024,1024]^T -------------------
// 128x128 tile, BK=32, 256 threads (2x2 waves, 4x4 16x16x32 MFMAs each).
// MODE 0: RoPE+0.125 bf16 (q)  MODE 1: RoPE bf16 (k)
// MODE 2: bf16 row-major (v)   MODE 3: fp32 (proj out)
template <int MODE>
__device__ __forceinline__ void mfma_gemm_body(
    __bf16* __restrict__ smem,
    const __bf16* __restrict__ A, const __bf16* __restrict__ B,
    void* __restrict__ Cv, const float2* __restrict__ sc)
{
    __bf16* As = smem;
    __bf16* Bs = smem + 4096;

    const int tid  = threadIdx.x;
    const int wave = tid >> 6, lane = tid & 63;
    const int lq   = lane & 15, quad = lane >> 4;
    const int row0 = blockIdx.y * 128, col0 = blockIdx.x * 128;
    const int mb   = (wave >> 1) * 64, nb = (wave & 1) * 64;

    const int srow = wave * 32 + (lane >> 2);
    const int scol = (lane & 3) << 3;
    const __bf16* Ag = A + (size_t)(row0 + srow) * DM + scol;
    const __bf16* Bg = B + (size_t)(col0 + srow) * DM + scol;
    __bf16* Al = As + wave * 1024;
    __bf16* Bl = Bs + wave * 1024;

    f32x4 acc[4][4] = {};

    for (int k0 = 0; k0 < DM; k0 += 32) {
        gll16(Ag + k0,           Al);
        gll16(Ag + k0 + 16 * DM, Al + 512);
        gll16(Bg + k0,           Bl);
        gll16(Bg + k0 + 16 * DM, Bl + 512);
        __syncthreads();

        bf16x8 af[4], bfr[4];
        #pragma unroll
        for (int mt = 0; mt < 4; ++mt)
            af[mt] = *(const bf16x8*)&As[(mb + mt * 16 + lq) * 32 + quad * 8];
        #pragma unroll
        for (int nt = 0; nt < 4; ++nt)
            bfr[nt] = *(const bf16x8*)&Bs[(nb + nt * 16 + lq) * 32 + quad * 8];
        #pragma unroll
        for (int mt = 0; mt < 4; ++mt)
            #pragma unroll
            for (int nt = 0; nt < 4; ++nt)
                acc[mt][nt] = __builtin_amdgcn_mfma_f32_16x16x32_bf16(
                    af[mt], bfr[nt], acc[mt][nt], 0, 0, 0);
        __syncthreads();
    }

    // ---- epilogue: acc -> LDS (wave-private) -> row-per-lane -> coalesced stores ----
    float* Ls = (float*)smem + wave * (16 * 68);
    const int erow = lane >> 2;
    const int ecol = (lane & 3) << 4;

    #pragma unroll
    for (int mt = 0; mt < 4; ++mt) {
        #pragma unroll
        for (int nt = 0; nt < 4; ++nt)
            #pragma unroll
            for (int r = 0; r < 4; ++r)
                Ls[(quad * 4 + r) * 68 + lq + 16 * nt] = acc[mt][nt][r];

        float vrow[16];
        #pragma unroll
        for (int jj = 0; jj < 4; ++jj)
            *(f32x4*)&vrow[jj * 4] = *(const f32x4*)&Ls[erow * 68 + ecol + jj * 4];

        const int grow = row0 + mb + mt * 16 + erow;
        if (MODE <= 1) {
            const float2* scp = sc + ((size_t)(grow & (SEQ - 1)) << 5) + (ecol >> 1);
            __bf16 ob[16];
            #pragma unroll
            for (int j = 0; j < 8; ++j) {
                const float2 cspr = scp[j];
                const float x1 = vrow[2 * j], x2 = vrow[2 * j + 1];
                float o0 = x1 * cspr.x - x2 * cspr.y;
                float o1 = x2 * cspr.x + x1 * cspr.y;
                if (MODE == 0) { o0 *= 0.125f; o1 *= 0.125f; }
                ob[2 * j]     = (__bf16)o0;
                ob[2 * j + 1] = (__bf16)o1;
            }
            __bf16* cp = (__bf16*)Cv + (size_t)grow * DM + col0 + nb + ecol;
            *(float4*)cp       = *(float4*)ob;
            *(float4*)(cp + 8) = *(float4*)(ob + 8);
        } else if (MODE == 2) {
            __bf16 ob[16];
            #pragma unroll
            for (int j = 0; j < 16; ++j) ob[j] = (__bf16)vrow[j];
            __bf16* cp = (__bf16*)Cv + (size_t)grow * DM + col0 + nb + ecol;
            *(float4*)cp       = *(float4*)ob;
            *(float4*)(cp + 8) = *(float4*)(ob + 8);
        } else {
            float* cp = (float*)Cv + (size_t)grow * DM + col0 + nb + ecol;
            #pragma unroll
            for (int jj = 0; jj < 4; ++jj)
                *(float4*)(cp + jj * 4) = *(float4*)&vrow[jj * 4];
        }
    }
}

__global__ __launch_bounds__(256, 4) void qkv_kernel(
    const __bf16* __restrict__ xb, const __bf16* __restrict__ wqb,
    const __bf16* __restrict__ wkb, const __bf16* __restrict__ wvb,
    __bf16* __restrict__ q, __bf16* __restrict__ k, __bf16* __restrict__ v,
    const float2* __restrict__ sc)
{
    __shared__ __align__(16) __bf16 SmemRaw[8704];   // single 17408 B allocation
    const int z = blockIdx.z;
    if (z == 0)      mfma_gemm_body<0>(SmemRaw, xb, wqb, q, sc);
    else if (z == 1) mfma_gemm_body<1>(SmemRaw, xb, wkb, k, sc);
    else             mfma_gemm_body<2>(SmemRaw, xb, wvb, v, sc);
}

__global__ __launch_bounds__(256, 4) void proj_kernel(
    const __bf16* __restrict__ aob, const __bf16* __restrict__ wob,
    float* __restrict__ out)
{
    __shared__ __align__(16) __bf16 SmemRaw[8704];
    mfma_gemm_body<3>(SmemRaw, aob, wob, out, nullptr);
}

// ---------------- V transpose: v[b][s][h*64+d] -> vt[b][h][d][s] ----------------------
__global__ __launch_bounds__(256) void vtrans_kernel(
    const __bf16* __restrict__ v, __bf16* __restrict__ vt)
{
    __shared__ __bf16 Ts[64][72];
    const int tid = threadIdx.x;
    const int s0  = blockIdx.x * 64;
    const int bh  = blockIdx.y;
    const int b = bh >> 4, h = bh & 15;

    {
        const int sl = tid >> 2, d0 = (tid & 3) << 4;
        const __bf16* gp = v + (size_t)(b * SEQ + s0 + sl) * DM + h * 64 + d0;
        *(float4*)&Ts[sl][d0]     = *(const float4*)gp;
        *(float4*)&Ts[sl][d0 + 8] = *(const float4*)(gp + 8);
    }
    __syncthreads();

    {
        const int dl = tid >> 2, sB = (tid & 3) << 4;
        __bf16 c[16];
        #pragma unroll
        for (int j = 0; j < 16; ++j) c[j] = Ts[sB + j][dl];
        __bf16* gp = vt + (size_t)(bh * 64 + dl) * SEQ + s0 + sB;
        *(float4*)gp       = *(float4*)c;
        *(float4*)(gp + 8) = *(float4*)(c + 8);
    }
}

// ---------------- MFMA flash attention v4 -------------------------------------------
// 256 threads (4 waves), 64 q-rows/block, 512 paired blocks = 2 blocks/CU.
// 128 keys staged per iteration (halves barrier pairs). S computed TRANSPOSED
// (S^T = K Q^T, operand swap): each lane holds one q-row (col=lane&15) with 4
// consecutive keys per reg -> P stores are ds_write_b64, l is a single scalar/lane.
// Register prefetch of stage st+1 during compute. Fixed-shift softmax.
// LDS strides 68/132 bf16 (== 2 dwords mod 4): measured 0 bank conflicts (r9).
__global__ __launch_bounds__(256, 2) void attn_kernel(
    const __bf16* __restrict__ Q, const __bf16* __restrict__ K,
    const __bf16* __restrict__ Vt, __bf16* __restrict__ O)
{
    __shared__ __bf16 Ks[128][68];      // [key][dh]
    __shared__ __bf16 Vs[64][132];      // [dh][key]
    __shared__ __bf16 Ps[4][16][132];   // wave-private P[qrow][key]

    const int tid  = threadIdx.x;
    const int wave = tid >> 6;
    const int lane = tid & 63;
    const int lq   = lane & 15;
    const int quad = lane >> 4;
    const int xpair = blockIdx.x, bh = blockIdx.y;
    const int b = bh >> 4, h = bh & 15;
    const size_t qkoff = (size_t)b * SEQ * DM + h * 64;
    const size_t vtoff = (size_t)bh * 64 * SEQ;

    // staging maps: 64 B (4 float4) per thread per buffer
    const int kr = tid >> 1, kc0 = (tid & 1) << 5;   // K: 128 rows x 64 cols
    const int vr = tid >> 2, vc0 = (tid & 3) << 5;   // V: 64 rows x 128 cols
    const __bf16* kgb = K  + qkoff + (size_t)kr * DM  + kc0;
    const __bf16* vgb = Vt + vtoff + (size_t)vr * SEQ + vc0;

    #pragma unroll
    for (int phase = 0; phase < 2; ++phase) {
        const int qt = phase ? xpair : (31 - xpair);
        const int row_base = qt * 64 + wave * 16;
        const int nst = (qt + 2) >> 1;              // stages of 128 keys

        // Q fragment (B-operand): row row_base+lq, pre-scaled by 1/8 in qkv epilogue
        const __bf16* qp = Q + qkoff + (size_t)(row_base + lq) * DM + quad * 8;
        const bf16x8 bq0 = *(const bf16x8*)qp;
        const bf16x8 bq1 = *(const bf16x8*)(qp + 32);

        // prime stage 0 into registers
        float4 kf[4], vf[4];
        #pragma unroll
        for (int i = 0; i < 4; ++i) {
            kf[i] = *(const float4*)(kgb + i * 8);
            vf[i] = *(const float4*)(vgb + i * 8);
        }

        __syncthreads();   // previous phase's LDS reads complete
        #pragma unroll
        for (int i = 0; i < 4; ++i) {
            *(float4*)&Ks[kr][kc0 + i * 8] = kf[i];
            *(float4*)&Vs[vr][vc0 + i * 8] = vf[i];
        }
        __syncthreads();

        f32x4 o[4] = {};
        float l_part = 0.f;

        for (int st = 0; st < nst; ++st) {
            if (st + 1 < nst) {   // prefetch next 128-key stage into registers
                const __bf16* kp = kgb + (size_t)(st + 1) * 128 * DM;
                const __bf16* vp = vgb + (st + 1) * 128;
                #pragma unroll
                for (int i = 0; i < 4; ++i) {
                    kf[i] = *(const float4*)(kp + i * 8);
                    vf[i] = *(const float4*)(vp + i * 8);
                }
            }

            if (st * 128 <= row_base + 15) {   // wave has unmasked work
                // S^T: 8 key16-tiles, A = K rows, B = Q rows
                f32x4 s[8];
                #pragma unroll
                for (int t = 0; t < 8; ++t) {
                    const bf16x8 ak0 = *(const bf16x8*)&Ks[t * 16 + lq][quad * 8];
                    const bf16x8 ak1 = *(const bf16x8*)&Ks[t * 16 + lq][32 + quad * 8];
                    f32x4 z = {};
                    z = __builtin_amdgcn_mfma_f32_16x16x32_bf16(ak0, bq0, z, 0, 0, 0);
                    s[t] = __builtin_amdgcn_mfma_f32_16x16x32_bf16(ak1, bq1, z, 0, 0, 0);
                }

                // mask + exp + pack P (keys st*128+16t+quad*4+r, qrow row_base+lq)
                #pragma unroll
                for (int t = 0; t < 8; ++t) {
                    const int kb = st * 128 + t * 16;
                    if (kb + 15 > row_base) {
                        #pragma unroll
                        for (int r = 0; r < 4; ++r)
                            if (kb + quad * 4 + r > row_base + lq) s[t][r] = -INFINITY;
                    }
                    __bf16 pb[4];
                    #pragma unroll
                    for (int r = 0; r < 4; ++r) {
                        const float e = __expf(s[t][r]);
                        l_part += e;
                        pb[r] = (__bf16)e;
                    }
                    *(float2*)&Ps[wave][lq][t * 16 + quad * 4] = *(float2*)pb;
                }

                // O += P V over 4 key-chunks of 32
                #pragma unroll
                for (int kc = 0; kc < 4; ++kc) {
                    const bf16x8 ap = *(const bf16x8*)&Ps[wave][lq][kc * 32 + quad * 8];
                    #pragma unroll
                    for (int nt = 0; nt < 4; ++nt) {
                        const bf16x8 bv =
                            *(const bf16x8*)&Vs[lq + 16 * nt][kc * 32 + quad * 8];
                        o[nt] = __builtin_amdgcn_mfma_f32_16x16x32_bf16(ap, bv, o[nt], 0, 0, 0);
                    }
                }
            }

            if (st + 1 < nst) {
                __syncthreads();   // all waves done reading Ks/Vs
                #pragma unroll
                for (int i = 0; i < 4; ++i) {
                    *(float4*)&Ks[kr][kc0 + i * 8] = kf[i];
                    *(float4*)&Vs[vr][vc0 + i * 8] = vf[i];
                }
                __syncthreads();
            }
        }

        // l: reduce over quads (same q-row lives in lanes lq, lq+16, lq+32, lq+48)
        l_part += __shfl_xor(l_part, 16, 64);
        l_part += __shfl_xor(l_part, 32, 64);

        // write O: o[nt] C-layout row = qrow-local quad*4+r, col lq -> d = lq+16nt
        #pragma unroll
        for (int r = 0; r < 4; ++r) {
            const float lr = __shfl(l_part, quad * 4 + r, 64);   // l of that q-row
            const float invl = 1.f / lr;
            const size_t row = (size_t)b * SEQ + row_base + quad * 4 + r;
            __bf16* op = O + row * DM + h * 64 + lq;
            #pragma unroll
            for (int nt = 0; nt < 4; ++nt)
                op[16 * nt] = (__bf16)(o[nt][r] * invl);
        }
    }
}

extern "C" void kernel_launch(void* const* d_in, const int* in_sizes, int n_in,
                              void* d_out, int out_size, void* d_ws, size_t ws_size,
                              hipStream_t stream)
{
    const float* x  = (const float*)d_in[0];
    const int*  pos = (const int*)d_in[1];
    const float* Wq = (const float*)d_in[2];
    const float* Wk = (const float*)d_in[3];
    const float* Wv = (const float*)d_in[4];
    const float* Wo = (const float*)d_in[5];
    float* out = (float*)d_out;

    __bf16* xb  = (__bf16*)d_ws;            // 8 MB
    __bf16* wqb = xb  + (size_t)XN;         // 2 MB each
    __bf16* wkb = wqb + (size_t)WN;
    __bf16* wvb = wkb + (size_t)WN;
    __bf16* wob = wvb + (size_t)WN;
    __bf16* q   = wob + (size_t)WN;         // 8 MB
    __bf16* k   = q   + (size_t)XN;         // 8 MB
    __bf16* v   = k   + (size_t)XN;         // 8 MB, row-major
    __bf16* vt  = v   + (size_t)XN;         // 8 MB, [b][h][dh][seq]
    __bf16* aob = vt  + (size_t)XN;         // 8 MB
    float2* sc  = (float2*)(aob + (size_t)XN);   // 512 KB RoPE table

    cvt_kernel<<<CVT_BLOCKS + TAB_N / 256, 256, 0, stream>>>(
        x, Wq, Wk, Wv, Wo, pos, xb, wqb, wkb, wvb, wob, sc);
    qkv_kernel<<<dim3(DM / 128, MTOT / 128, 3), 256, 0, stream>>>(
        xb, wqb, wkb, wvb, q, k, v, sc);
    vtrans_kernel<<<dim3(SEQ / 64, 2 * NHEAD), 256, 0, stream>>>(v, vt);
    attn_kernel<<<dim3(16, 2 * NHEAD), 256, 0, stream>>>(q, k, vt, aob);
    proj_kernel<<<dim3(DM / 128, MTOT / 128), 256, 0, stream>>>(aob, wob, out);
}

// Round 11
// 195.817 us; speedup vs baseline: 1.2984x; 1.2984x over previous
//
#include <hip/hip_runtime.h>
#include <math.h>

#define SEQ   2048
#define DM    1024
#define MTOT  4096      // batch * seq
#define NHEAD 16
#define DHEAD 64
#define ROPE_C 0.41524101186091903f   // log2(10000)/32
#define XN    (MTOT * DM)             // 4194304
#define WN    (DM * DM)               // 1048576
#define CVT_BLOCKS ((XN + 4 * WN) / (8 * 256))   // 4096
#define TAB_N      (SEQ * 32)                    // 65536 float2

typedef __bf16 bf16x8 __attribute__((ext_vector_type(8)));
typedef float  f32x4  __attribute__((ext_vector_type(4)));

// async global->LDS, 16 B/lane; lds dest = wave-uniform base + lane*16
__device__ __forceinline__ void gll16(const __bf16* gp, __bf16* lp) {
    __builtin_amdgcn_global_load_lds(
        (const __attribute__((address_space(1))) unsigned int*)gp,
        (__attribute__((address_space(3))) unsigned int*)lp,
        16, 0, 0);
}

// -------- fp32 -> bf16 conversion of x + 4 weights, and RoPE sin/cos table ------------
__global__ __launch_bounds__(256) void cvt_kernel(
    const float* __restrict__ x,  const float* __restrict__ wq,
    const float* __restrict__ wk, const float* __restrict__ wv,
    const float* __restrict__ wo, const int* __restrict__ pos,
    __bf16* __restrict__ xb,  __bf16* __restrict__ wqb,
    __bf16* __restrict__ wkb, __bf16* __restrict__ wvb,
    __bf16* __restrict__ wob, float2* __restrict__ sc)
{
    if (blockIdx.x >= CVT_BLOCKS) {   // sin/cos table: sc[s][ip] = (cos, sin)
        const int idx = (blockIdx.x - CVT_BLOCKS) * 256 + threadIdx.x;
        if (idx < TAB_N) {
            const int p_i = idx >> 5, ip = idx & 31;
            const float ang = (float)pos[p_i] * exp2f(-(float)ip * ROPE_C);
            float sn, cs;
            sincosf(ang, &sn, &cs);
            sc[idx] = make_float2(cs, sn);
        }
        return;
    }
    const size_t i8 = ((size_t)blockIdx.x * 256 + threadIdx.x) * 8;
    const float* s; __bf16* d; size_t off;
    if      (i8 < XN)          { s = x;  d = xb;  off = i8; }
    else if (i8 < XN + WN)     { s = wq; d = wqb; off = i8 - XN; }
    else if (i8 < XN + 2 * WN) { s = wk; d = wkb; off = i8 - XN - (size_t)WN; }
    else if (i8 < XN + 3 * WN) { s = wv; d = wvb; off = i8 - XN - 2 * (size_t)WN; }
    else                       { s = wo; d = wob; off = i8 - XN - 3 * (size_t)WN; }
    const float4 a = *(const float4*)(s + off);
    const float4 b = *(const float4*)(s + off + 4);
    __bf16 o[8] = {(__bf16)a.x, (__bf16)a.y, (__bf16)a.z, (__bf16)a.w,
                   (__bf16)b.x, (__bf16)b.y, (__bf16)b.z, (__bf16)b.w};
    *(float4*)(d + off) = *(float4*)o;
}

// ---------------- MFMA GEMM: C[M,1024] = A[M,1024] @ B[1024,1024]^T -------------------
// 128x128 tile, BK=32, 256 threads (2x2 waves, 4x4 16x16x32 MFMAs each).
// MODE 0: RoPE+0.125 bf16 (q)  MODE 1: RoPE bf16 (k)
// MODE 2: bf16 row-major (v)   MODE 3: fp32 (proj out)
template <int MODE>
__device__ __forceinline__ void mfma_gemm_body(
    __bf16* __restrict__ smem,
    const __bf16* __restrict__ A, const __bf16* __restrict__ B,
    void* __restrict__ Cv, const float2* __restrict__ sc)
{
    __bf16* As = smem;
    __bf16* Bs = smem + 4096;

    const int tid  = threadIdx.x;
    const int wave = tid >> 6, lane = tid & 63;
    const int lq   = lane & 15, quad = lane >> 4;
    const int row0 = blockIdx.y * 128, col0 = blockIdx.x * 128;
    const int mb   = (wave >> 1) * 64, nb = (wave & 1) * 64;

    const int srow = wave * 32 + (lane >> 2);
    const int scol = (lane & 3) << 3;
    const __bf16* Ag = A + (size_t)(row0 + srow) * DM + scol;
    const __bf16* Bg = B + (size_t)(col0 + srow) * DM + scol;
    __bf16* Al = As + wave * 1024;
    __bf16* Bl = Bs + wave * 1024;

    f32x4 acc[4][4] = {};

    for (int k0 = 0; k0 < DM; k0 += 32) {
        gll16(Ag + k0,           Al);
        gll16(Ag + k0 + 16 * DM, Al + 512);
        gll16(Bg + k0,           Bl);
        gll16(Bg + k0 + 16 * DM, Bl + 512);
        __syncthreads();

        bf16x8 af[4], bfr[4];
        #pragma unroll
        for (int mt = 0; mt < 4; ++mt)
            af[mt] = *(const bf16x8*)&As[(mb + mt * 16 + lq) * 32 + quad * 8];
        #pragma unroll
        for (int nt = 0; nt < 4; ++nt)
            bfr[nt] = *(const bf16x8*)&Bs[(nb + nt * 16 + lq) * 32 + quad * 8];
        #pragma unroll
        for (int mt = 0; mt < 4; ++mt)
            #pragma unroll
            for (int nt = 0; nt < 4; ++nt)
                acc[mt][nt] = __builtin_amdgcn_mfma_f32_16x16x32_bf16(
                    af[mt], bfr[nt], acc[mt][nt], 0, 0, 0);
        __syncthreads();
    }

    // ---- epilogue: acc -> LDS (wave-private) -> row-per-lane -> coalesced stores ----
    float* Ls = (float*)smem + wave * (16 * 68);
    const int erow = lane >> 2;
    const int ecol = (lane & 3) << 4;

    #pragma unroll
    for (int mt = 0; mt < 4; ++mt) {
        #pragma unroll
        for (int nt = 0; nt < 4; ++nt)
            #pragma unroll
            for (int r = 0; r < 4; ++r)
                Ls[(quad * 4 + r) * 68 + lq + 16 * nt] = acc[mt][nt][r];

        float vrow[16];
        #pragma unroll
        for (int jj = 0; jj < 4; ++jj)
            *(f32x4*)&vrow[jj * 4] = *(const f32x4*)&Ls[erow * 68 + ecol + jj * 4];

        const int grow = row0 + mb + mt * 16 + erow;
        if (MODE <= 1) {
            const float2* scp = sc + ((size_t)(grow & (SEQ - 1)) << 5) + (ecol >> 1);
            __bf16 ob[16];
            #pragma unroll
            for (int j = 0; j < 8; ++j) {
                const float2 cspr = scp[j];
                const float x1 = vrow[2 * j], x2 = vrow[2 * j + 1];
                float o0 = x1 * cspr.x - x2 * cspr.y;
                float o1 = x2 * cspr.x + x1 * cspr.y;
                if (MODE == 0) { o0 *= 0.125f; o1 *= 0.125f; }
                ob[2 * j]     = (__bf16)o0;
                ob[2 * j + 1] = (__bf16)o1;
            }
            __bf16* cp = (__bf16*)Cv + (size_t)grow * DM + col0 + nb + ecol;
            *(float4*)cp       = *(float4*)ob;
            *(float4*)(cp + 8) = *(float4*)(ob + 8);
        } else if (MODE == 2) {
            __bf16 ob[16];
            #pragma unroll
            for (int j = 0; j < 16; ++j) ob[j] = (__bf16)vrow[j];
            __bf16* cp = (__bf16*)Cv + (size_t)grow * DM + col0 + nb + ecol;
            *(float4*)cp       = *(float4*)ob;
            *(float4*)(cp + 8) = *(float4*)(ob + 8);
        } else {
            float* cp = (float*)Cv + (size_t)grow * DM + col0 + nb + ecol;
            #pragma unroll
            for (int jj = 0; jj < 4; ++jj)
                *(float4*)(cp + jj * 4) = *(float4*)&vrow[jj * 4];
        }
    }
}

__global__ __launch_bounds__(256, 4) void qkv_kernel(
    const __bf16* __restrict__ xb, const __bf16* __restrict__ wqb,
    const __bf16* __restrict__ wkb, const __bf16* __restrict__ wvb,
    __bf16* __restrict__ q, __bf16* __restrict__ k, __bf16* __restrict__ v,
    const float2* __restrict__ sc)
{
    __shared__ __align__(16) __bf16 SmemRaw[8704];   // single 17408 B allocation
    const int z = blockIdx.z;
    if (z == 0)      mfma_gemm_body<0>(SmemRaw, xb, wqb, q, sc);
    else if (z == 1) mfma_gemm_body<1>(SmemRaw, xb, wkb, k, sc);
    else             mfma_gemm_body<2>(SmemRaw, xb, wvb, v, sc);
}

__global__ __launch_bounds__(256, 4) void proj_kernel(
    const __bf16* __restrict__ aob, const __bf16* __restrict__ wob,
    float* __restrict__ out)
{
    __shared__ __align__(16) __bf16 SmemRaw[8704];
    mfma_gemm_body<3>(SmemRaw, aob, wob, out, nullptr);
}

// ---------------- V transpose: v[b][s][h*64+d] -> vt[b][h][d][s] ----------------------
__global__ __launch_bounds__(256) void vtrans_kernel(
    const __bf16* __restrict__ v, __bf16* __restrict__ vt)
{
    __shared__ __bf16 Ts[64][72];
    const int tid = threadIdx.x;
    const int s0  = blockIdx.x * 64;
    const int bh  = blockIdx.y;
    const int b = bh >> 4, h = bh & 15;

    {
        const int sl = tid >> 2, d0 = (tid & 3) << 4;
        const __bf16* gp = v + (size_t)(b * SEQ + s0 + sl) * DM + h * 64 + d0;
        *(float4*)&Ts[sl][d0]     = *(const float4*)gp;
        *(float4*)&Ts[sl][d0 + 8] = *(const float4*)(gp + 8);
    }
    __syncthreads();

    {
        const int dl = tid >> 2, sB = (tid & 3) << 4;
        __bf16 c[16];
        #pragma unroll
        for (int j = 0; j < 16; ++j) c[j] = Ts[sB + j][dl];
        __bf16* gp = vt + (size_t)(bh * 64 + dl) * SEQ + s0 + sB;
        *(float4*)gp       = *(float4*)c;
        *(float4*)(gp + 8) = *(float4*)(c + 8);
    }
}

// ---------------- MFMA flash attention v5 (r9 base + LDS double-buffer) --------------
// 256 threads (4 waves), 64 q-rows/block, 512 paired blocks = 2 blocks/CU.
// Double-buffered Ks/Vs: iteration kt reads buf[kt&1], writes prefetched tile kt+1
// to buf[(kt+1)&1] -> ONE barrier per iteration (r9 had two). Register prefetch of
// K/V tile kt+1 during compute. Q fragments direct from global. Fixed-shift softmax.
// LDS strides 68/76 bf16: measured 0 bank conflicts (r9).
__global__ __launch_bounds__(256, 2) void attn_kernel(
    const __bf16* __restrict__ Q, const __bf16* __restrict__ K,
    const __bf16* __restrict__ Vt, __bf16* __restrict__ O)
{
    __shared__ __bf16 Ks[2][64][68];    // [buf][key][dh]
    __shared__ __bf16 Vs[2][64][68];    // [buf][dh][key]
    __shared__ __bf16 Ps[4][16][76];    // wave-private P tiles

    const int tid  = threadIdx.x;
    const int wave = tid >> 6;
    const int lane = tid & 63;
    const int lq   = lane & 15;
    const int quad = lane >> 4;
    const int xpair = blockIdx.x, bh = blockIdx.y;
    const int b = bh >> 4, h = bh & 15;
    const size_t qkoff = (size_t)b * SEQ * DM + h * 64;
    const size_t vtoff = (size_t)bh * 64 * SEQ;

    // staging map: 32 B per thread per buffer (64 rows x 64 cols bf16)
    const int r_ = tid >> 2, c_ = (tid & 3) << 4;
    const __bf16* kg = K  + qkoff + (size_t)r_ * DM  + c_;
    const __bf16* vg = Vt + vtoff + (size_t)r_ * SEQ + c_;

    #pragma unroll
    for (int phase = 0; phase < 2; ++phase) {
        const int qt = phase ? xpair : (31 - xpair);
        const int row_base = qt * 64 + wave * 16;
        const int ntiles = qt + 1;

        // Q fragments straight from global (q is pre-scaled by 1/8 in qkv epilogue)
        const __bf16* qp = Q + qkoff + (size_t)(row_base + lq) * DM + quad * 8;
        const bf16x8 aq0 = *(const bf16x8*)qp;
        const bf16x8 aq1 = *(const bf16x8*)(qp + 32);

        // prime: tile 0 into registers
        float4 k0 = *(const float4*)kg, k1 = *(const float4*)(kg + 8);
        float4 v0 = *(const float4*)vg, v1 = *(const float4*)(vg + 8);

        __syncthreads();   // previous phase's LDS reads complete
        *(float4*)&Ks[0][r_][c_]     = k0;
        *(float4*)&Ks[0][r_][c_ + 8] = k1;
        *(float4*)&Vs[0][r_][c_]     = v0;
        *(float4*)&Vs[0][r_][c_ + 8] = v1;
        __syncthreads();

        f32x4 o[4] = {};
        float l_part[4] = {0.f, 0.f, 0.f, 0.f};

        for (int kt = 0; kt < ntiles; ++kt) {
            const int cb = kt & 1;          // compute buffer
            // prefetch next tile into registers while computing this one
            if (kt + 1 < ntiles) {
                const __bf16* kp = kg + (size_t)(kt + 1) * 64 * DM;
                const __bf16* vp = vg + (kt + 1) * 64;
                k0 = *(const float4*)kp; k1 = *(const float4*)(kp + 8);
                v0 = *(const float4*)vp; v1 = *(const float4*)(vp + 8);
            }

            // S = Q K^T
            f32x4 s[4] = {};
            #pragma unroll
            for (int nt = 0; nt < 4; ++nt) {
                const bf16x8 bk0 = *(const bf16x8*)&Ks[cb][lq + 16 * nt][quad * 8];
                const bf16x8 bk1 = *(const bf16x8*)&Ks[cb][lq + 16 * nt][32 + quad * 8];
                s[nt] = __builtin_amdgcn_mfma_f32_16x16x32_bf16(aq0, bk0, s[nt], 0, 0, 0);
                s[nt] = __builtin_amdgcn_mfma_f32_16x16x32_bf16(aq1, bk1, s[nt], 0, 0, 0);
            }

            if (kt == qt) {    // diagonal tile: causal mask
                const int myrow = row_base + quad * 4;
                const int key0 = kt * 64;
                #pragma unroll
                for (int nt = 0; nt < 4; ++nt)
                    #pragma unroll
                    for (int r = 0; r < 4; ++r)
                        if (key0 + lq + 16 * nt > myrow + r) s[nt][r] = -INFINITY;
            }

            // fixed-shift softmax: P = exp(s)
            #pragma unroll
            for (int nt = 0; nt < 4; ++nt)
                #pragma unroll
                for (int r = 0; r < 4; ++r) {
                    const float e = __expf(s[nt][r]);
                    s[nt][r] = e;
                    l_part[r] += e;
                }

            #pragma unroll
            for (int nt = 0; nt < 4; ++nt)
                #pragma unroll
                for (int r = 0; r < 4; ++r)
                    Ps[wave][quad * 4 + r][lq + 16 * nt] = (__bf16)s[nt][r];

            const bf16x8 ap0 = *(const bf16x8*)&Ps[wave][lq][quad * 8];
            const bf16x8 ap1 = *(const bf16x8*)&Ps[wave][lq][32 + quad * 8];
            #pragma unroll
            for (int nt = 0; nt < 4; ++nt) {
                const bf16x8 bv0 = *(const bf16x8*)&Vs[cb][lq + 16 * nt][quad * 8];
                const bf16x8 bv1 = *(const bf16x8*)&Vs[cb][lq + 16 * nt][32 + quad * 8];
                o[nt] = __builtin_amdgcn_mfma_f32_16x16x32_bf16(ap0, bv0, o[nt], 0, 0, 0);
                o[nt] = __builtin_amdgcn_mfma_f32_16x16x32_bf16(ap1, bv1, o[nt], 0, 0, 0);
            }

            if (kt + 1 < ntiles) {
                const int nb_ = cb ^ 1;     // write buffer (nobody reads it this iter)
                *(float4*)&Ks[nb_][r_][c_]     = k0;
                *(float4*)&Ks[nb_][r_][c_ + 8] = k1;
                *(float4*)&Vs[nb_][r_][c_]     = v0;
                *(float4*)&Vs[nb_][r_][c_ + 8] = v1;
                __syncthreads();   // single barrier: publishes writes, protects reads
            }
        }

        // reduce l over the 16 column-lanes, write O
        #pragma unroll
        for (int r = 0; r < 4; ++r) {
            float l = l_part[r];
            l += __shfl_xor(l, 1, 64);
            l += __shfl_xor(l, 2, 64);
            l += __shfl_xor(l, 4, 64);
            l += __shfl_xor(l, 8, 64);
            const float invl = 1.f / l;
            const size_t row = (size_t)b * SEQ + row_base + quad * 4 + r;
            __bf16* op = O + row * DM + h * 64 + lq;
            #pragma unroll
            for (int nt = 0; nt < 4; ++nt)
                op[16 * nt] = (__bf16)(o[nt][r] * invl);
        }
    }
}

extern "C" void kernel_launch(void* const* d_in, const int* in_sizes, int n_in,
                              void* d_out, int out_size, void* d_ws, size_t ws_size,
                              hipStream_t stream)
{
    const float* x  = (const float*)d_in[0];
    const int*  pos = (const int*)d_in[1];
    const float* Wq = (const float*)d_in[2];
    const float* Wk = (const float*)d_in[3];
    const float* Wv = (const float*)d_in[4];
    const float* Wo = (const float*)d_in[5];
    float* out = (float*)d_out;

    __bf16* xb  = (__bf16*)d_ws;            // 8 MB
    __bf16* wqb = xb  + (size_t)XN;         // 2 MB each
    __bf16* wkb = wqb + (size_t)WN;
    __bf16* wvb = wkb + (size_t)WN;
    __bf16* wob = wvb + (size_t)WN;
    __bf16* q   = wob + (size_t)WN;         // 8 MB
    __bf16* k   = q   + (size_t)XN;         // 8 MB
    __bf16* v   = k   + (size_t)XN;         // 8 MB, row-major
    __bf16* vt  = v   + (size_t)XN;         // 8 MB, [b][h][dh][seq]
    __bf16* aob = vt  + (size_t)XN;         // 8 MB
    float2* sc  = (float2*)(aob + (size_t)XN);   // 512 KB RoPE table

    cvt_kernel<<<CVT_BLOCKS + TAB_N / 256, 256, 0, stream>>>(
        x, Wq, Wk, Wv, Wo, pos, xb, wqb, wkb, wvb, wob, sc);
    qkv_kernel<<<dim3(DM / 128, MTOT / 128, 3), 256, 0, stream>>>(
        xb, wqb, wkb, wvb, q, k, v, sc);
    vtrans_kernel<<<dim3(SEQ / 64, 2 * NHEAD), 256, 0, stream>>>(v, vt);
    attn_kernel<<<dim3(16, 2 * NHEAD), 256, 0, stream>>>(q, k, vt, aob);
    proj_kernel<<<dim3(DM / 128, MTOT / 128), 256, 0, stream>>>(aob, wob, out);
}

// Round 12
// 191.042 us; speedup vs baseline: 1.3309x; 1.0250x over previous
//
#include <hip/hip_runtime.h>
#include <math.h>

#define SEQ   2048
#define DM    1024
#define MTOT  4096      // batch * seq
#define NHEAD 16
#define DHEAD 64
#define ROPE_C 0.41524101186091903f   // log2(10000)/32
#define XN    (MTOT * DM)             // 4194304
#define WN    (DM * DM)               // 1048576
#define CVT_BLOCKS ((XN + 4 * WN) / (8 * 256))   // 4096
#define TAB_N      (SEQ * 32)                    // 65536 float2

typedef __bf16 bf16x8 __attribute__((ext_vector_type(8)));
typedef float  f32x4  __attribute__((ext_vector_type(4)));

// async global->LDS, 16 B/lane; lds dest = wave-uniform base + lane*16
__device__ __forceinline__ void gll16(const __bf16* gp, __bf16* lp) {
    __builtin_amdgcn_global_load_lds(
        (const __attribute__((address_space(1))) unsigned int*)gp,
        (__attribute__((address_space(3))) unsigned int*)lp,
        16, 0, 0);
}

// -------- fp32 -> bf16 conversion of x + 4 weights, and RoPE sin/cos table ------------
__global__ __launch_bounds__(256) void cvt_kernel(
    const float* __restrict__ x,  const float* __restrict__ wq,
    const float* __restrict__ wk, const float* __restrict__ wv,
    const float* __restrict__ wo, const int* __restrict__ pos,
    __bf16* __restrict__ xb,  __bf16* __restrict__ wqb,
    __bf16* __restrict__ wkb, __bf16* __restrict__ wvb,
    __bf16* __restrict__ wob, float2* __restrict__ sc)
{
    if (blockIdx.x >= CVT_BLOCKS) {   // sin/cos table: sc[s][ip] = (cos, sin)
        const int idx = (blockIdx.x - CVT_BLOCKS) * 256 + threadIdx.x;
        if (idx < TAB_N) {
            const int p_i = idx >> 5, ip = idx & 31;
            const float ang = (float)pos[p_i] * exp2f(-(float)ip * ROPE_C);
            float sn, cs;
            sincosf(ang, &sn, &cs);
            sc[idx] = make_float2(cs, sn);
        }
        return;
    }
    const size_t i8 = ((size_t)blockIdx.x * 256 + threadIdx.x) * 8;
    const float* s; __bf16* d; size_t off;
    if      (i8 < XN)          { s = x;  d = xb;  off = i8; }
    else if (i8 < XN + WN)     { s = wq; d = wqb; off = i8 - XN; }
    else if (i8 < XN + 2 * WN) { s = wk; d = wkb; off = i8 - XN - (size_t)WN; }
    else if (i8 < XN + 3 * WN) { s = wv; d = wvb; off = i8 - XN - 2 * (size_t)WN; }
    else                       { s = wo; d = wob; off = i8 - XN - 3 * (size_t)WN; }
    const float4 a = *(const float4*)(s + off);
    const float4 b = *(const float4*)(s + off + 4);
    __bf16 o[8] = {(__bf16)a.x, (__bf16)a.y, (__bf16)a.z, (__bf16)a.w,
                   (__bf16)b.x, (__bf16)b.y, (__bf16)b.z, (__bf16)b.w};
    *(float4*)(d + off) = *(float4*)o;
}

// ---------------- MFMA GEMM: C[M,1024] = A[M,1024] @ B[1024,1024]^T -------------------
// 128x128 tile, BK=32, 256 threads (2x2 waves, 4x4 16x16x32 MFMAs each).
// MODE 0: RoPE+0.125 bf16 (q)  MODE 1: RoPE bf16 (k)
// MODE 2: bf16 row-major (v)   MODE 3: fp32 (proj out)
template <int MODE>
__device__ __forceinline__ void mfma_gemm_body(
    __bf16* __restrict__ smem,
    const __bf16* __restrict__ A, const __bf16* __restrict__ B,
    void* __restrict__ Cv, const float2* __restrict__ sc)
{
    __bf16* As = smem;
    __bf16* Bs = smem + 4096;

    const int tid  = threadIdx.x;
    const int wave = tid >> 6, lane = tid & 63;
    const int lq   = lane & 15, quad = lane >> 4;
    const int row0 = blockIdx.y * 128, col0 = blockIdx.x * 128;
    const int mb   = (wave >> 1) * 64, nb = (wave & 1) * 64;

    const int srow = wave * 32 + (lane >> 2);
    const int scol = (lane & 3) << 3;
    const __bf16* Ag = A + (size_t)(row0 + srow) * DM + scol;
    const __bf16* Bg = B + (size_t)(col0 + srow) * DM + scol;
    __bf16* Al = As + wave * 1024;
    __bf16* Bl = Bs + wave * 1024;

    f32x4 acc[4][4] = {};

    for (int k0 = 0; k0 < DM; k0 += 32) {
        gll16(Ag + k0,           Al);
        gll16(Ag + k0 + 16 * DM, Al + 512);
        gll16(Bg + k0,           Bl);
        gll16(Bg + k0 + 16 * DM, Bl + 512);
        __syncthreads();

        bf16x8 af[4], bfr[4];
        #pragma unroll
        for (int mt = 0; mt < 4; ++mt)
            af[mt] = *(const bf16x8*)&As[(mb + mt * 16 + lq) * 32 + quad * 8];
        #pragma unroll
        for (int nt = 0; nt < 4; ++nt)
            bfr[nt] = *(const bf16x8*)&Bs[(nb + nt * 16 + lq) * 32 + quad * 8];
        #pragma unroll
        for (int mt = 0; mt < 4; ++mt)
            #pragma unroll
            for (int nt = 0; nt < 4; ++nt)
                acc[mt][nt] = __builtin_amdgcn_mfma_f32_16x16x32_bf16(
                    af[mt], bfr[nt], acc[mt][nt], 0, 0, 0);
        __syncthreads();
    }

    // ---- epilogue: acc -> LDS (wave-private) -> row-per-lane -> coalesced stores ----
    float* Ls = (float*)smem + wave * (16 * 68);
    const int erow = lane >> 2;
    const int ecol = (lane & 3) << 4;

    #pragma unroll
    for (int mt = 0; mt < 4; ++mt) {
        #pragma unroll
        for (int nt = 0; nt < 4; ++nt)
            #pragma unroll
            for (int r = 0; r < 4; ++r)
                Ls[(quad * 4 + r) * 68 + lq + 16 * nt] = acc[mt][nt][r];

        float vrow[16];
        #pragma unroll
        for (int jj = 0; jj < 4; ++jj)
            *(f32x4*)&vrow[jj * 4] = *(const f32x4*)&Ls[erow * 68 + ecol + jj * 4];

        const int grow = row0 + mb + mt * 16 + erow;
        if (MODE <= 1) {
            const float2* scp = sc + ((size_t)(grow & (SEQ - 1)) << 5) + (ecol >> 1);
            __bf16 ob[16];
            #pragma unroll
            for (int j = 0; j < 8; ++j) {
                const float2 cspr = scp[j];
                const float x1 = vrow[2 * j], x2 = vrow[2 * j + 1];
                float o0 = x1 * cspr.x - x2 * cspr.y;
                float o1 = x2 * cspr.x + x1 * cspr.y;
                if (MODE == 0) { o0 *= 0.125f; o1 *= 0.125f; }
                ob[2 * j]     = (__bf16)o0;
                ob[2 * j + 1] = (__bf16)o1;
            }
            __bf16* cp = (__bf16*)Cv + (size_t)grow * DM + col0 + nb + ecol;
            *(float4*)cp       = *(float4*)ob;
            *(float4*)(cp + 8) = *(float4*)(ob + 8);
        } else if (MODE == 2) {
            __bf16 ob[16];
            #pragma unroll
            for (int j = 0; j < 16; ++j) ob[j] = (__bf16)vrow[j];
            __bf16* cp = (__bf16*)Cv + (size_t)grow * DM + col0 + nb + ecol;
            *(float4*)cp       = *(float4*)ob;
            *(float4*)(cp + 8) = *(float4*)(ob + 8);
        } else {
            float* cp = (float*)Cv + (size_t)grow * DM + col0 + nb + ecol;
            #pragma unroll
            for (int jj = 0; jj < 4; ++jj)
                *(float4*)(cp + jj * 4) = *(float4*)&vrow[jj * 4];
        }
    }
}

__global__ __launch_bounds__(256, 4) void qkv_kernel(
    const __bf16* __restrict__ xb, const __bf16* __restrict__ wqb,
    const __bf16* __restrict__ wkb, const __bf16* __restrict__ wvb,
    __bf16* __restrict__ q, __bf16* __restrict__ k, __bf16* __restrict__ v,
    const float2* __restrict__ sc)
{
    __shared__ __align__(16) __bf16 SmemRaw[8704];   // single 17408 B allocation
    const int z = blockIdx.z;
    if (z == 0)      mfma_gemm_body<0>(SmemRaw, xb, wqb, q, sc);
    else if (z == 1) mfma_gemm_body<1>(SmemRaw, xb, wkb, k, sc);
    else             mfma_gemm_body<2>(SmemRaw, xb, wvb, v, sc);
}

__global__ __launch_bounds__(256, 4) void proj_kernel(
    const __bf16* __restrict__ aob, const __bf16* __restrict__ wob,
    float* __restrict__ out)
{
    __shared__ __align__(16) __bf16 SmemRaw[8704];
    mfma_gemm_body<3>(SmemRaw, aob, wob, out, nullptr);
}

// ---------------- V transpose: v[b][s][h*64+d] -> vt[b][h][d][s] ----------------------
__global__ __launch_bounds__(256) void vtrans_kernel(
    const __bf16* __restrict__ v, __bf16* __restrict__ vt)
{
    __shared__ __bf16 Ts[64][72];
    const int tid = threadIdx.x;
    const int s0  = blockIdx.x * 64;
    const int bh  = blockIdx.y;
    const int b = bh >> 4, h = bh & 15;

    {
        const int sl = tid >> 2, d0 = (tid & 3) << 4;
        const __bf16* gp = v + (size_t)(b * SEQ + s0 + sl) * DM + h * 64 + d0;
        *(float4*)&Ts[sl][d0]     = *(const float4*)gp;
        *(float4*)&Ts[sl][d0 + 8] = *(const float4*)(gp + 8);
    }
    __syncthreads();

    {
        const int dl = tid >> 2, sB = (tid & 3) << 4;
        __bf16 c[16];
        #pragma unroll
        for (int j = 0; j < 16; ++j) c[j] = Ts[sB + j][dl];
        __bf16* gp = vt + (size_t)(bh * 64 + dl) * SEQ + s0 + sB;
        *(float4*)gp       = *(float4*)c;
        *(float4*)(gp + 8) = *(float4*)(c + 8);
    }
}

// ---------------- MFMA flash attention v6 (r9 structure + transposed S) --------------
// 256 threads (4 waves), 64 q-rows/block, 512 paired blocks = 2 blocks/CU.
// r9 staging: single-buffer Ks/Vs, register prefetch of tile kt+1, 2 barriers/iter
// (empirically beats single-barrier dbuf, r11). Compute is TRANSPOSED (r10 math,
// verified): S^T = mfma(A=K-rows, B=Q-rows) -> lane owns ONE q-row (n=lq) and 4
// consecutive keys per reg. P-stores: 4x ds_write_b64 (was 16x b16). l: single
// scalar/lane, reduced once per phase (was 16 shuffles/iter). PV: O = mfma(A=P,
// B=V^T) with both fragments contiguous b128 reads. Fixed-shift softmax.
// LDS strides 68/76: measured 0 bank conflicts (r9).
__global__ __launch_bounds__(256, 2) void attn_kernel(
    const __bf16* __restrict__ Q, const __bf16* __restrict__ K,
    const __bf16* __restrict__ Vt, __bf16* __restrict__ O)
{
    __shared__ __bf16 Ks[64][68];       // [key][dh]
    __shared__ __bf16 Vs[64][68];       // [dh][key]
    __shared__ __bf16 Ps[4][16][76];    // wave-private P[qrow][key]

    const int tid  = threadIdx.x;
    const int wave = tid >> 6;
    const int lane = tid & 63;
    const int lq   = lane & 15;
    const int quad = lane >> 4;
    const int xpair = blockIdx.x, bh = blockIdx.y;
    const int b = bh >> 4, h = bh & 15;
    const size_t qkoff = (size_t)b * SEQ * DM + h * 64;
    const size_t vtoff = (size_t)bh * 64 * SEQ;

    // staging map: 32 B per thread per buffer (64 rows x 64 cols bf16)
    const int r_ = tid >> 2, c_ = (tid & 3) << 4;
    const __bf16* kg = K  + qkoff + (size_t)r_ * DM  + c_;
    const __bf16* vg = Vt + vtoff + (size_t)r_ * SEQ + c_;

    #pragma unroll
    for (int phase = 0; phase < 2; ++phase) {
        const int qt = phase ? xpair : (31 - xpair);
        const int row_base = qt * 64 + wave * 16;
        const int ntiles = qt + 1;

        // Q fragment (B-operand): q-row = row_base + lq (pre-scaled by 1/8)
        const __bf16* qp = Q + qkoff + (size_t)(row_base + lq) * DM + quad * 8;
        const bf16x8 bq0 = *(const bf16x8*)qp;
        const bf16x8 bq1 = *(const bf16x8*)(qp + 32);

        // prime: tile 0 into registers
        float4 k0 = *(const float4*)kg, k1 = *(const float4*)(kg + 8);
        float4 v0 = *(const float4*)vg, v1 = *(const float4*)(vg + 8);

        __syncthreads();   // previous phase's LDS reads complete
        *(float4*)&Ks[r_][c_]     = k0;
        *(float4*)&Ks[r_][c_ + 8] = k1;
        *(float4*)&Vs[r_][c_]     = v0;
        *(float4*)&Vs[r_][c_ + 8] = v1;
        __syncthreads();

        f32x4 o[4] = {};
        float l_part = 0.f;

        for (int kt = 0; kt < ntiles; ++kt) {
            // prefetch next tile into registers while computing this one
            if (kt + 1 < ntiles) {
                const __bf16* kp = kg + (size_t)(kt + 1) * 64 * DM;
                const __bf16* vp = vg + (kt + 1) * 64;
                k0 = *(const float4*)kp; k1 = *(const float4*)(kp + 8);
                v0 = *(const float4*)vp; v1 = *(const float4*)(vp + 8);
            }

            // S^T: lane -> q-row = row_base+lq, keys kt*64 + t*16 + quad*4 + r
            f32x4 s[4];
            #pragma unroll
            for (int t = 0; t < 4; ++t) {
                const bf16x8 ak0 = *(const bf16x8*)&Ks[t * 16 + lq][quad * 8];
                const bf16x8 ak1 = *(const bf16x8*)&Ks[t * 16 + lq][32 + quad * 8];
                f32x4 z = {};
                z = __builtin_amdgcn_mfma_f32_16x16x32_bf16(ak0, bq0, z, 0, 0, 0);
                s[t] = __builtin_amdgcn_mfma_f32_16x16x32_bf16(ak1, bq1, z, 0, 0, 0);
            }

            if (kt == qt) {    // diagonal tile: causal mask (key > q-row)
                const int myq = row_base + lq;
                #pragma unroll
                for (int t = 0; t < 4; ++t) {
                    const int kb = kt * 64 + t * 16 + quad * 4;
                    #pragma unroll
                    for (int r = 0; r < 4; ++r)
                        if (kb + r > myq) s[t][r] = -INFINITY;
                }
            }

            // fixed-shift softmax: P = exp(s); pack 4 consecutive keys -> b64 store
            #pragma unroll
            for (int t = 0; t < 4; ++t) {
                __bf16 pb[4];
                #pragma unroll
                for (int r = 0; r < 4; ++r) {
                    const float e = __expf(s[t][r]);
                    l_part += e;
                    pb[r] = (__bf16)e;
                }
                *(float2*)&Ps[wave][lq][t * 16 + quad * 4] = *(float2*)pb;
            }

            // O = P V  (A = P rows, B = V^T rows), keys in 2 chunks of 32
            #pragma unroll
            for (int kc = 0; kc < 2; ++kc) {
                const bf16x8 ap = *(const bf16x8*)&Ps[wave][lq][kc * 32 + quad * 8];
                #pragma unroll
                for (int nt = 0; nt < 4; ++nt) {
                    const bf16x8 bv = *(const bf16x8*)&Vs[lq + 16 * nt][kc * 32 + quad * 8];
                    o[nt] = __builtin_amdgcn_mfma_f32_16x16x32_bf16(ap, bv, o[nt], 0, 0, 0);
                }
            }

            if (kt + 1 < ntiles) {
                __syncthreads();   // all waves done reading Ks/Vs
                *(float4*)&Ks[r_][c_]     = k0;
                *(float4*)&Ks[r_][c_ + 8] = k1;
                *(float4*)&Vs[r_][c_]     = v0;
                *(float4*)&Vs[r_][c_ + 8] = v1;
                __syncthreads();
            }
        }

        // l: quad-copies of the same q-row live in lanes lq, lq+16, lq+32, lq+48
        l_part += __shfl_xor(l_part, 16, 64);
        l_part += __shfl_xor(l_part, 32, 64);

        // write O: o[nt][r] = O[q = row_base + quad*4 + r][d = lq + 16*nt]
        #pragma unroll
        for (int r = 0; r < 4; ++r) {
            const float lr = __shfl(l_part, quad * 4 + r, 64);
            const float invl = 1.f / lr;
            const size_t row = (size_t)b * SEQ + row_base + quad * 4 + r;
            __bf16* op = O + row * DM + h * 64 + lq;
            #pragma unroll
            for (int nt = 0; nt < 4; ++nt)
                op[16 * nt] = (__bf16)(o[nt][r] * invl);
        }
    }
}

extern "C" void kernel_launch(void* const* d_in, const int* in_sizes, int n_in,
                              void* d_out, int out_size, void* d_ws, size_t ws_size,
                              hipStream_t stream)
{
    const float* x  = (const float*)d_in[0];
    const int*  pos = (const int*)d_in[1];
    const float* Wq = (const float*)d_in[2];
    const float* Wk = (const float*)d_in[3];
    const float* Wv = (const float*)d_in[4];
    const float* Wo = (const float*)d_in[5];
    float* out = (float*)d_out;

    __bf16* xb  = (__bf16*)d_ws;            // 8 MB
    __bf16* wqb = xb  + (size_t)XN;         // 2 MB each
    __bf16* wkb = wqb + (size_t)WN;
    __bf16* wvb = wkb + (size_t)WN;
    __bf16* wob = wvb + (size_t)WN;
    __bf16* q   = wob + (size_t)WN;         // 8 MB
    __bf16* k   = q   + (size_t)XN;         // 8 MB
    __bf16* v   = k   + (size_t)XN;         // 8 MB, row-major
    __bf16* vt  = v   + (size_t)XN;         // 8 MB, [b][h][dh][seq]
    __bf16* aob = vt  + (size_t)XN;         // 8 MB
    float2* sc  = (float2*)(aob + (size_t)XN);   // 512 KB RoPE table

    cvt_kernel<<<CVT_BLOCKS + TAB_N / 256, 256, 0, stream>>>(
        x, Wq, Wk, Wv, Wo, pos, xb, wqb, wkb, wvb, wob, sc);
    qkv_kernel<<<dim3(DM / 128, MTOT / 128, 3), 256, 0, stream>>>(
        xb, wqb, wkb, wvb, q, k, v, sc);
    vtrans_kernel<<<dim3(SEQ / 64, 2 * NHEAD), 256, 0, stream>>>(v, vt);
    attn_kernel<<<dim3(16, 2 * NHEAD), 256, 0, stream>>>(q, k, vt, aob);
    proj_kernel<<<dim3(DM / 128, MTOT / 128), 256, 0, stream>>>(aob, wob, out);
}